// Round 8
// baseline (141.337 us; speedup 1.0000x reference)
//
#include <hip/hip_runtime.h>
#include <math.h>

typedef unsigned short ushortT;
typedef unsigned int uintT;
typedef __attribute__((ext_vector_type(8))) short short8;
typedef __attribute__((ext_vector_type(16))) float f32x16;
#define MFMA32(a, b, c) __builtin_amdgcn_mfma_f32_32x32x16_bf16((a), (b), (c), 0, 0, 0)

// MFMA 32x32x16 layouts (gfx950, HW-verified m74/m101/m120):
//  A-frag: lane reads A[m = lane&31][k = (lane>>5)*8 + j], j=0..7
//  B-frag: lane reads B[k = (lane>>5)*8 + j][n = lane&31]
//  C/D:    col = lane&31, row = (reg&3) + 8*(reg>>2) + 4*(lane>>5)

#define LOG2E 1.4426950408889634f

static __device__ __forceinline__ ushortT f2b(float f) {
    union { float f; uintT u; } v; v.f = f;
    uintT u = v.u;
    u += 0x7fffu + ((u >> 16) & 1u);     // round-to-nearest-even
    return (ushortT)(u >> 16);
}
static __device__ __forceinline__ uintT pack2(float a, float b) {
    return (uintT)f2b(a) | ((uintT)f2b(b) << 16);
}
// truncating bf16 pack of two fp32 in ONE v_perm_b32 (low16=a, high16=b)
static __device__ __forceinline__ uintT pack2t(float a, float b) {
    union { float f; uintT u; } x0, x1; x0.f = a; x1.f = b;
    return __builtin_amdgcn_perm(x1.u, x0.u, 0x07060302u);
}
static __device__ __forceinline__ float blo(uintT u) {
    union { uintT u; float f; } v; v.u = u << 16; return v.f;
}
static __device__ __forceinline__ float bhi(uintT u) {
    union { uintT u; float f; } v; v.u = u & 0xffff0000u; return v.f;
}
static __device__ __forceinline__ f32x16 zero16() {
    f32x16 z;
    #pragma unroll
    for (int i = 0; i < 16; ++i) z[i] = 0.f;
    return z;
}

#define NQB 16
#define NKB 32

// ---------------------------------------------------------------------------
// Prep: weight transposes only (x conversion fused into qkv A-stage, R15).
// Blocks 0..767: Wqkv [512][1536] -> Wqt [1536][512] bf16.
// Blocks 768..1023: Wproj [512][512] -> Wpt [512][512] bf16.
// ---------------------------------------------------------------------------
__global__ __launch_bounds__(256) void prep_kernel(
    const float* __restrict__ Wq, ushortT* __restrict__ Wqt,
    const float* __restrict__ Wp, ushortT* __restrict__ Wpt) {
    const int bid = blockIdx.x, t = threadIdx.x;
    __shared__ float tile[32][33];
    const float* W; ushortT* Wt; int C, c0, r0;
    if (bid < 768) {
        const int b = bid;
        W = Wq; Wt = Wqt; C = 1536;
        c0 = (b % 48) * 32; r0 = (b / 48) * 32;
    } else {
        const int b = bid - 768;
        W = Wp; Wt = Wpt; C = 512;
        c0 = (b & 15) * 32; r0 = (b >> 4) * 32;
    }
    const int tx = t & 31, ty = t >> 5;
    #pragma unroll
    for (int i = 0; i < 4; ++i)
        tile[ty + 8 * i][tx] = W[(size_t)(r0 + ty + 8 * i) * C + c0 + tx];
    __syncthreads();
    #pragma unroll
    for (int i = 0; i < 4; ++i) {
        int rr = ty + 8 * i;
        Wt[(size_t)(c0 + rr) * 512 + r0 + tx] = f2b(tile[tx][rr]);
    }
}

// ---------------------------------------------------------------------------
// QKV GEMM (bf16 MFMA): 128x64 tiles, grid (24,32) = 768 blocks = 3/CU.
// Reads x fp32 directly (R15); cos fused in epilogue (R14).
// ---------------------------------------------------------------------------
__global__ __launch_bounds__(256) void qkv_gemm_kernel(
    const float* __restrict__ x, const ushortT* __restrict__ wt,
    const float* __restrict__ bias,
    ushortT* __restrict__ qb, ushortT* __restrict__ kbuf, ushortT* __restrict__ vt,
    float* __restrict__ qm, float* __restrict__ km,
    float* __restrict__ qs, float* __restrict__ ks) {
    __shared__ __align__(16) ushortT As[2][128 * 40];
    __shared__ __align__(16) ushortT Bs[2][64 * 40];
    __shared__ float sumbuf[4][64];
    __shared__ float meanS[2][64];
    __shared__ float wminS[4];
    const int t = threadIdx.x;
    const int l = t & 63, w = t >> 6;
    const int lm = l & 31, lh = l >> 5;
    const int rowbase = blockIdx.y * 128;
    const int colbase = blockIdx.x * 64;

    f32x16 acc[2];
    acc[0] = zero16(); acc[1] = zero16();

    // A loader: thread -> row t>>1 (0..127), k-half t&1 (16 fp32 elems)
    const int r = t >> 1, half = t & 1;
    const float* Agf = x + (size_t)(rowbase + r) * 512 + half * 16;
    const int soA = r * 40 + half * 16;
    // B loader: thread -> row t>>2 (0..63), k-quarter t&3 (8 elems)
    const int rb = t >> 2, q4 = t & 3;
    const ushortT* Bg = wt + (size_t)(colbase + rb) * 512 + q4 * 8;
    const int soB = rb * 40 + q4 * 8;

    float4 af0, af1, af2, af3; uint4 b0;
    af0 = *(const float4*)(Agf);     af1 = *(const float4*)(Agf + 4);
    af2 = *(const float4*)(Agf + 8); af3 = *(const float4*)(Agf + 12);
    b0 = *(const uint4*)(Bg);
    *(uint4*)(&As[0][soA]) = make_uint4(pack2(af0.x, af0.y), pack2(af0.z, af0.w),
                                        pack2(af1.x, af1.y), pack2(af1.z, af1.w));
    *(uint4*)(&As[0][soA] + 8) = make_uint4(pack2(af2.x, af2.y), pack2(af2.z, af2.w),
                                            pack2(af3.x, af3.y), pack2(af3.z, af3.w));
    *(uint4*)(&Bs[0][soB]) = b0;

    for (int k0 = 0; k0 < 512; k0 += 32) {
        const int cur = (k0 >> 5) & 1;
        __syncthreads();
        if (k0 < 480) {
            const int kn = k0 + 32;
            af0 = *(const float4*)(Agf + kn);      af1 = *(const float4*)(Agf + kn + 4);
            af2 = *(const float4*)(Agf + kn + 8);  af3 = *(const float4*)(Agf + kn + 12);
            b0 = *(const uint4*)(Bg + kn);
        }
        #pragma unroll
        for (int ks2 = 0; ks2 < 2; ++ks2) {
            const int ko = 16 * ks2 + 8 * lh;
            short8 af  = *(const short8*)(&As[cur][(32 * w + lm) * 40 + ko]);
            short8 b_0 = *(const short8*)(&Bs[cur][lm * 40 + ko]);
            short8 b_1 = *(const short8*)(&Bs[cur][(32 + lm) * 40 + ko]);
            acc[0] = MFMA32(af, b_0, acc[0]);
            acc[1] = MFMA32(af, b_1, acc[1]);
        }
        if (k0 < 480) {
            const int nxt = cur ^ 1;
            *(uint4*)(&As[nxt][soA]) = make_uint4(pack2(af0.x, af0.y), pack2(af0.z, af0.w),
                                                  pack2(af1.x, af1.y), pack2(af1.z, af1.w));
            *(uint4*)(&As[nxt][soA] + 8) = make_uint4(pack2(af2.x, af2.y), pack2(af2.z, af2.w),
                                                      pack2(af3.x, af3.y), pack2(af3.z, af3.w));
            *(uint4*)(&Bs[nxt][soB]) = b0;
        }
    }

    // epilogue: 64-col tile = exactly one (which, head)
    const int which = blockIdx.x >> 3;            // 0=q 1=k 2=v
    const int h = blockIdx.x & 7;
    const int by = blockIdx.y;
    const int b = by >> 4;
    const size_t hb = (size_t)(b * 8 + h);
    float bias2[2];
    #pragma unroll
    for (int nt = 0; nt < 2; ++nt) bias2[nt] = bias[colbase + 32 * nt + lm];
    float msum[2] = {0.f, 0.f};
    #pragma unroll
    for (int nt = 0; nt < 2; ++nt) {
        const int dd = 32 * nt + lm;
        #pragma unroll
        for (int rg = 0; rg < 16; ++rg) {
            const int row_local = 32 * w + (rg & 3) + 8 * (rg >> 2) + 4 * lh;
            const int ll = (rowbase + row_local) & 2047;
            float val = acc[nt][rg] + bias2[nt];
            if (which == 0) {
                val *= 0.125f;
                msum[nt] += val;
                qb[(hb * 2048 + ll) * 64 + dd] = f2b(val * LOG2E);
            } else if (which == 1) {
                msum[nt] += val;
                kbuf[(hb * 2048 + ll) * 64 + dd] = f2b(val);
            } else {
                vt[hb * 131072 + (size_t)(ll >> 6) * 4096 + dd * 64 + (ll & 63)] = f2b(val);
            }
            acc[nt][rg] = val;   // keep for fused cosine
        }
    }
    if (which == 2) return;
    #pragma unroll
    for (int nt = 0; nt < 2; ++nt) {
        float s = msum[nt] + __shfl_xor(msum[nt], 32);   // full 32-row col sum
        if (l < 32) sumbuf[w][32 * nt + lm] = s;
    }
    __syncthreads();
    // block means -> global + LDS (for cosine)
    if (which == 0) {
        if (t < 64) {
            const int qbi = by & 15;
            const float m =
                (sumbuf[0][t] + sumbuf[1][t] + sumbuf[2][t] + sumbuf[3][t]) * (1.0f / 128.0f);
            qm[(hb * 16 + qbi) * 64 + t] = m;
            meanS[0][t] = m;
        }
    } else {
        if (t < 128) {
            const int d = t & 63, pair = t >> 6;      // pair 0: waves 0-1, 1: waves 2-3
            const int kbi = 2 * (by & 15) + pair;
            const float m =
                (sumbuf[2 * pair][d] + sumbuf[2 * pair + 1][d]) * (1.0f / 64.0f);
            km[(hb * 32 + kbi) * 64 + d] = m;
            meanS[pair][d] = m;
        }
    }
    __syncthreads();
    // fused min-cosine-to-mean: thread holds cols {lm, 32+lm} of 16 rows
    {
        const int mrow = (which == 0) ? 0 : (w >> 1);
        const float mv0 = meanS[mrow][lm], mv1 = meanS[mrow][32 + lm];
        float mn2 = mv0 * mv0 + mv1 * mv1;
        #pragma unroll
        for (int off = 1; off < 32; off <<= 1) mn2 += __shfl_xor(mn2, off);
        const float mnorm = sqrtf(mn2);
        float cmin = 1e30f;
        #pragma unroll
        for (int rg = 0; rg < 16; ++rg) {
            float dp = acc[0][rg] * mv0 + acc[1][rg] * mv1;
            float nn = acc[0][rg] * acc[0][rg] + acc[1][rg] * acc[1][rg];
            #pragma unroll
            for (int off = 1; off < 32; off <<= 1) {
                dp += __shfl_xor(dp, off);
                nn += __shfl_xor(nn, off);
            }
            const float cosv = dp / ((sqrtf(nn) + 1e-6f) * (mnorm + 1e-6f));
            cmin = fminf(cmin, cosv);
        }
        cmin = fminf(cmin, __shfl_xor(cmin, 32));
        if (l == 0) wminS[w] = cmin;
    }
    __syncthreads();
    if (t == 0) {
        if (which == 0) {
            qs[hb * 16 + (by & 15)] =
                fminf(fminf(wminS[0], wminS[1]), fminf(wminS[2], wminS[3]));
        } else {
            ks[hb * 32 + 2 * (by & 15)]     = fminf(wminS[0], wminS[1]);
            ks[hb * 32 + 2 * (by & 15) + 1] = fminf(wminS[2], wminS[3]);
        }
    }
}

// ---------------------------------------------------------------------------
// Flash attention, bf16 MFMA, S^T form, exp2 softmax, inline mask (R14).
// ROUND-18: REVERT to the R14-proven attn structure (best total 135.4us):
// KVBLK=128 (2 K-blocks/iter), 70KB LDS -> 2 blocks/CU co-residency, which
// beat R17's KVBLK=256 1-block/CU by ~6us (cross-block overlap hides the
// barrier drains; m114 wave-overlap effect). launch_bounds(512,2), flat
// body (no lambda -- R17 proved the lambda caused 100MB scratch spill).
// Keeps R15 prep-fusion (qkv reads x directly) -- independent, bit-exact.
// 512 threads = 8 waves = 2 q-col groups (qc) x 4 key quarters (kq).
// Epilogue: 4 key-quarter partials reduced in LDS, divide by l, write ob.
// ---------------------------------------------------------------------------
#define KS_SH (128 * 72)
#define VS_SH (64 * 136)
__global__ __launch_bounds__(512, 2) void attn_kernel(
    const ushortT* __restrict__ qb, const ushortT* __restrict__ kbuf,
    const ushortT* __restrict__ vt,
    const float* __restrict__ qm, const float* __restrict__ km,
    const float* __restrict__ qs, const float* __restrict__ ks,
    ushortT* __restrict__ ob) {
    // main-loop LDS: Ks[2][128key][72], Vs[2][64d][136key-pad] = 70 KB
    // epilogue aliases the same region: ox uint4[6][8][64] (48K) + lx (1.5K)
    __shared__ __align__(16) ushortT smem[2 * KS_SH + 2 * VS_SH];
    __shared__ int klist[33];
    __shared__ float qmS[64];
    __shared__ float pnS[32];
    ushortT (*Ks)[KS_SH] = (ushortT(*)[KS_SH])smem;
    ushortT (*Vs)[VS_SH] = (ushortT(*)[VS_SH])(smem + 2 * KS_SH);

    const int t = threadIdx.x;
    const int l = t & 63, w = t >> 6;
    const int lm = l & 31, lh = l >> 5;
    const int qc = w >> 2, kq = w & 3;        // q 64-group, key 32-quarter
    const int bh = blockIdx.x, qt = blockIdx.y;

    if (t < 64) qmS[t] = qm[((size_t)bh * 16 + qt) * 64 + t];

    // Q B-frags straight from global: wave qc owns q rows [64qc, 64qc+64)
    const ushortT* qg = qb + ((size_t)bh * 2048 + qt * 128) * 64;
    short8 qf[4][2];
    #pragma unroll
    for (int qh = 0; qh < 2; ++qh)
        #pragma unroll
        for (int ksd = 0; ksd < 4; ++ksd)
            qf[ksd][qh] = *(const short8*)(qg + (64 * qc + 32 * qh + lm) * 64 + 16 * ksd + 8 * lh);
    __syncthreads();   // qmS visible

    // inline mask row (wave 0, lanes < 32): pooled softmax + CDF keep
    if (w == 0 && l < 32) {
        const float* kmr = km + ((size_t)bh * 32 + l) * 64;
        float dot = 0.f;
        #pragma unroll
        for (int d = 0; d < 64; ++d) dot += qmS[d] * kmr[d];
        float mx = dot;
        #pragma unroll
        for (int off = 1; off < 32; off <<= 1) mx = fmaxf(mx, __shfl_xor(mx, off));
        const float e = expf(dot - mx);
        float sum = e;
        #pragma unroll
        for (int off = 1; off < 32; off <<= 1) sum += __shfl_xor(sum, off);
        const float pn = e * (1.0f / sum);
        pnS[l] = pn;
        float before = 0.f;
        #pragma unroll
        for (int j = 0; j < 32; ++j) {
            const float pj = pnS[j];
            if (pj > pn || (pj == pn && j < l)) before += pj;
        }
        const bool qfb = !(qs[bh * 16 + qt] > 0.6f);
        const bool kfb = !(ks[bh * 32 + l] > 0.6f);
        const bool keep = (before < 0.98f) || qfb || kfb;
        unsigned long long bal = __ballot(keep);
        if (keep) {
            const int rank = __popcll(bal & ((1ULL << l) - 1ULL));
            klist[rank] = l;
        }
        if (l == 0) klist[32] = __popcll(bal);
    }
    __syncthreads();   // klist visible

    const int cnt = klist[32];
    const int nIter = (cnt + 1) >> 1;

    // staging: thread -> tile (0,1: K kh / 2,3: V kh), 64 rows x 64 cols each,
    // 4 uint4 per thread
    const int tile = t >> 7, tt = t & 127;
    const int isV = tile >> 1, skh = tile & 1;
    const int srow = tt >> 1, shalf = (tt & 1) * 32;
    const ushortT* gsrc = (isV ? vt : kbuf) + (size_t)bh * 131072;
    const int goff = srow * 64 + shalf;   // K: [key][d] ; V(vt): [d][key]
    const int soff = isV ? (srow * 136 + skh * 64 + shalf)
                         : ((skh * 64 + srow) * 72 + shalf);
    ushortT* sd0 = (isV ? &Vs[0][soff] : &Ks[0][soff]);
    ushortT* sd1 = (isV ? &Vs[1][soff] : &Ks[1][soff]);

    f32x16 oacc[2][2];
    oacc[0][0] = zero16(); oacc[1][0] = zero16();
    oacc[0][1] = zero16(); oacc[1][1] = zero16();
    float l_i[2] = {0.f, 0.f};

    uint4 st0, st1, st2, st3;
    {   // prologue: stage iteration 0
        int kidx = skh; if (kidx >= cnt) kidx = cnt - 1;
        const ushortT* g = gsrc + (size_t)klist[kidx] * 4096 + goff;
        st0 = *(const uint4*)(g);      st1 = *(const uint4*)(g + 8);
        st2 = *(const uint4*)(g + 16); st3 = *(const uint4*)(g + 24);
        *(uint4*)(sd0)      = st0; *(uint4*)(sd0 + 8)  = st1;
        *(uint4*)(sd0 + 16) = st2; *(uint4*)(sd0 + 24) = st3;
    }

    for (int i = 0; i < nIter; ++i) {
        const int cur = i & 1;
        __syncthreads();
        if (i + 1 < nIter) {
            int kidx = 2 * (i + 1) + skh; if (kidx >= cnt) kidx = cnt - 1;
            const ushortT* g = gsrc + (size_t)klist[kidx] * 4096 + goff;
            st0 = *(const uint4*)(g);      st1 = *(const uint4*)(g + 8);
            st2 = *(const uint4*)(g + 16); st3 = *(const uint4*)(g + 24);
        }
        // this wave's 32 keys live in key-block half kq>>1 of this iteration
        const float mf = (2 * i + (kq >> 1) < cnt) ? 1.f : 0.f;
        // S^T = K * Q^T  (S already in log2e units)
        f32x16 sacc[2];
        sacc[0] = zero16(); sacc[1] = zero16();
        #pragma unroll
        for (int ksd = 0; ksd < 4; ++ksd) {
            const int ko = 16 * ksd + 8 * lh;
            short8 kf = *(const short8*)(&Ks[cur][(32 * kq + lm) * 72 + ko]);
            sacc[0] = MFMA32(kf, qf[ksd][0], sacc[0]);
            sacc[1] = MFMA32(kf, qf[ksd][1], sacc[1]);
        }
        // p = exp2(s) * mf (mf==1 except odd-cnt tail)
        uintT uu[2][4][2];   // [qh][rb][pair]
        #pragma unroll
        for (int qh = 0; qh < 2; ++qh) {
            float psum0 = 0.f, psum1 = 0.f;
            #pragma unroll
            for (int rp = 0; rp < 8; ++rp) {
                const float e0 = __builtin_amdgcn_exp2f(sacc[qh][2 * rp]) * mf;
                const float e1 = __builtin_amdgcn_exp2f(sacc[qh][2 * rp + 1]) * mf;
                psum0 += e0; psum1 += e1;
                uu[qh][rp >> 1][rp & 1] = pack2t(e0, e1);
            }
            float psum = psum0 + psum1;
            psum += __shfl_xor(psum, 32);
            l_i[qh] += psum;
        }
        // O^T += V^T * P^T ; P^T B-frag via lane pair-exchange
        #pragma unroll
        for (int ksk = 0; ksk < 2; ++ksk) {
            const int vko = 32 * kq + 16 * ksk + 8 * lh;
            short8 vf0 = *(const short8*)(&Vs[cur][lm * 136 + vko]);
            short8 vf1 = *(const short8*)(&Vs[cur][(32 + lm) * 136 + vko]);
            #pragma unroll
            for (int qh = 0; qh < 2; ++qh) {
                const uintT kA = lh ? uu[qh][2 * ksk + 1][0] : uu[qh][2 * ksk][0];
                const uintT kB = lh ? uu[qh][2 * ksk + 1][1] : uu[qh][2 * ksk][1];
                const uintT sA = lh ? uu[qh][2 * ksk][0] : uu[qh][2 * ksk + 1][0];
                const uintT sB = lh ? uu[qh][2 * ksk][1] : uu[qh][2 * ksk + 1][1];
                const uintT rA = (uintT)__shfl_xor((int)sA, 32);
                const uintT rB = (uintT)__shfl_xor((int)sB, 32);
                union { uintT u[4]; short8 v; } cv;
                if (lh == 0) { cv.u[0] = kA; cv.u[1] = kB; cv.u[2] = rA; cv.u[3] = rB; }
                else         { cv.u[0] = rA; cv.u[1] = rB; cv.u[2] = kA; cv.u[3] = kB; }
                oacc[0][qh] = MFMA32(vf0, cv.v, oacc[0][qh]);
                oacc[1][qh] = MFMA32(vf1, cv.v, oacc[1][qh]);
            }
        }
        if (i + 1 < nIter) {
            ushortT* sd = (cur ^ 1) ? sd1 : sd0;
            *(uint4*)(sd)      = st0; *(uint4*)(sd + 8)  = st1;
            *(uint4*)(sd + 16) = st2; *(uint4*)(sd + 24) = st3;
        }
    }

    // ---- cross-kq reduction in LDS (aliases dead K/V buffers) ----
    uint4* ox = (uint4*)smem;                          // [6 wslot][8 reg-grp][64 lane]
    float* lx = (float*)((char*)smem + 49152);         // [6 wslot][2 qh][32 lm]
    __syncthreads();
    if (kq != 0) {
        const int wslot = qc * 3 + (kq - 1);
        #pragma unroll
        for (int dt = 0; dt < 2; ++dt)
            #pragma unroll
            for (int qh = 0; qh < 2; ++qh)
                #pragma unroll
                for (int g2 = 0; g2 < 2; ++g2) {
                    uint4 u;
                    u.x = pack2(oacc[dt][qh][8 * g2 + 0], oacc[dt][qh][8 * g2 + 1]);
                    u.y = pack2(oacc[dt][qh][8 * g2 + 2], oacc[dt][qh][8 * g2 + 3]);
                    u.z = pack2(oacc[dt][qh][8 * g2 + 4], oacc[dt][qh][8 * g2 + 5]);
                    u.w = pack2(oacc[dt][qh][8 * g2 + 6], oacc[dt][qh][8 * g2 + 7]);
                    ox[(wslot * 8 + (dt * 4 + qh * 2 + g2)) * 64 + l] = u;
                }
        if (lh == 0) {
            lx[(wslot * 2 + 0) * 32 + lm] = l_i[0];
            lx[(wslot * 2 + 1) * 32 + lm] = l_i[1];
        }
    }
    __syncthreads();
    if (kq == 0) {
        float lt[2] = {l_i[0], l_i[1]};
        #pragma unroll
        for (int p = 0; p < 3; ++p) {
            const int ws2 = qc * 3 + p;
            lt[0] += lx[(ws2 * 2 + 0) * 32 + lm];
            lt[1] += lx[(ws2 * 2 + 1) * 32 + lm];
            #pragma unroll
            for (int dt = 0; dt < 2; ++dt)
                #pragma unroll
                for (int qh = 0; qh < 2; ++qh)
                    #pragma unroll
                    for (int g2 = 0; g2 < 2; ++g2) {
                        uint4 u = ox[(ws2 * 8 + (dt * 4 + qh * 2 + g2)) * 64 + l];
                        oacc[dt][qh][8 * g2 + 0] += blo(u.x);
                        oacc[dt][qh][8 * g2 + 1] += bhi(u.x);
                        oacc[dt][qh][8 * g2 + 2] += blo(u.y);
                        oacc[dt][qh][8 * g2 + 3] += bhi(u.y);
                        oacc[dt][qh][8 * g2 + 4] += blo(u.z);
                        oacc[dt][qh][8 * g2 + 5] += bhi(u.z);
                        oacc[dt][qh][8 * g2 + 6] += blo(u.w);
                        oacc[dt][qh][8 * g2 + 7] += bhi(u.w);
                    }
        }
        #pragma unroll
        for (int qh = 0; qh < 2; ++qh) {
            const float inv = 1.0f / lt[qh];
            const int token = qt * 128 + qc * 64 + 32 * qh + lm;
            ushortT* orow = ob + ((size_t)bh * 2048 + token) * 64;
            #pragma unroll
            for (int dt = 0; dt < 2; ++dt)
                #pragma unroll
                for (int rp = 0; rp < 8; ++rp) {
                    const int d0 = 32 * dt + 8 * (rp >> 1) + 4 * lh + 2 * (rp & 1);
                    *(uintT*)(orow + d0) =
                        pack2(oacc[dt][qh][2 * rp] * inv, oacc[dt][qh][2 * rp + 1] * inv);
                }
        }
    }
}

// ---------------------------------------------------------------------------
// Proj GEMM: 64x64 tiles, grid (8,64) = 512 blocks = 2 waves/SIMD.
// ob (gathered [4096,512] bf16) @ Wprojt^T + bias -> out fp32.
// ---------------------------------------------------------------------------
__global__ __launch_bounds__(256) void proj_gemm_kernel(
    const ushortT* __restrict__ ob, const ushortT* __restrict__ wpt,
    const float* __restrict__ bias, float* __restrict__ out) {
    __shared__ __align__(16) ushortT As[2][64 * 40];
    __shared__ __align__(16) ushortT Bs[2][64 * 40];
    const int t = threadIdx.x;
    const int l = t & 63, w = t >> 6;
    const int lm = l & 31, lh = l >> 5;
    const int rh = w & 1, ch = w >> 1;            // wave -> 32-row half, 32-col half
    const int rowbase = blockIdx.y * 64;
    const int colbase = blockIdx.x * 64;

    f32x16 acc = zero16();

    const int r = t >> 2, q4 = t & 3;             // row 0..63, k-quarter (8 elems)
    const int token = rowbase + r;
    const int b2 = token >> 11, lt = token & 2047;
    const int so = r * 40 + q4 * 8;
    const ushortT* obbase = ob + ((size_t)(b2 * 8) * 2048 + lt) * 64 + q4 * 8;
    const ushortT* Bg = wpt + (size_t)(colbase + r) * 512 + q4 * 8;

    uint4 a0, b0;
    a0 = *(const uint4*)(obbase);
    b0 = *(const uint4*)(Bg);
    *(uint4*)(&As[0][so]) = a0;
    *(uint4*)(&Bs[0][so]) = b0;

    for (int k0 = 0; k0 < 512; k0 += 32) {
        const int cur = (k0 >> 5) & 1;
        __syncthreads();
        if (k0 < 480) {
            const int kn = k0 + 32;
            const ushortT* Ag = obbase + (size_t)(kn >> 6) * 131072 + (kn & 63);
            a0 = *(const uint4*)(Ag);
            b0 = *(const uint4*)(Bg + kn);
        }
        #pragma unroll
        for (int ks2 = 0; ks2 < 2; ++ks2) {
            const int ko = 16 * ks2 + 8 * lh;
            short8 af = *(const short8*)(&As[cur][(32 * rh + lm) * 40 + ko]);
            short8 bf = *(const short8*)(&Bs[cur][(32 * ch + lm) * 40 + ko]);
            acc = MFMA32(af, bf, acc);
        }
        if (k0 < 480) {
            const int nxt = cur ^ 1;
            *(uint4*)(&As[nxt][so]) = a0;
            *(uint4*)(&Bs[nxt][so]) = b0;
        }
    }
    const int c = colbase + 32 * ch + lm;
    const float bb = bias[c];
    #pragma unroll
    for (int rg = 0; rg < 16; ++rg) {
        const int row_local = 32 * rh + (rg & 3) + 8 * (rg >> 2) + 4 * lh;
        out[(size_t)(rowbase + row_local) * 512 + c] = acc[rg] + bb;
    }
}

// ---------------------------------------------------------------------------
extern "C" void kernel_launch(void* const* d_in, const int* in_sizes, int n_in,
                              void* d_out, int out_size, void* d_ws, size_t ws_size,
                              hipStream_t stream) {
    const float* x     = (const float*)d_in[0];
    const float* Wqkv  = (const float*)d_in[1];
    const float* bqkv  = (const float*)d_in[2];
    const float* Wproj = (const float*)d_in[3];
    const float* bproj = (const float*)d_in[4];
    float* out = (float*)d_out;

    char* w = (char*)d_ws;
    ushortT* wqkvt  = (ushortT*)(w + 4194304);          // 1.5 MB
    ushortT* wprojt = (ushortT*)(w + 5767168);          // 0.5 MB
    ushortT* qb     = (ushortT*)(w + 6291456);          // 4 MB (scaled 0.125*log2e)
    ushortT* kbuf   = (ushortT*)(w + 10485760);         // 4 MB
    ushortT* vt     = (ushortT*)(w + 14680064);         // 4 MB (transposed per k-block)
    ushortT* ob     = (ushortT*)(w + 18874368);         // 4 MB (final attention output)
    float*   qm     = (float*)(w + 23068672);           // 64 KB
    float*   km     = (float*)(w + 23134208);           // 128 KB
    float*   qs     = (float*)(w + 36406272);           // 1 KB
    float*   ks     = (float*)(w + 36407296);           // 2 KB

    prep_kernel<<<1024, 256, 0, stream>>>(Wqkv, wqkvt, Wproj, wprojt);
    qkv_gemm_kernel<<<dim3(24, 32), 256, 0, stream>>>(x, wqkvt, bqkv, qb, kbuf, vt,
                                                      qm, km, qs, ks);
    attn_kernel<<<dim3(16, 16), 512, 0, stream>>>(qb, kbuf, vt, qm, km, qs, ks, ob);
    proj_gemm_kernel<<<dim3(8, 64), 256, 0, stream>>>(ob, wprojt, bproj, out);
}

// Round 9
// 134.604 us; speedup vs baseline: 1.0500x; 1.0500x over previous
//
#include <hip/hip_runtime.h>
#include <math.h>

typedef unsigned short ushortT;
typedef unsigned int uintT;
typedef __attribute__((ext_vector_type(8))) short short8;
typedef __attribute__((ext_vector_type(16))) float f32x16;
#define MFMA32(a, b, c) __builtin_amdgcn_mfma_f32_32x32x16_bf16((a), (b), (c), 0, 0, 0)

// MFMA 32x32x16 layouts (gfx950, HW-verified m74/m101/m120):
//  A-frag: lane reads A[m = lane&31][k = (lane>>5)*8 + j], j=0..7
//  B-frag: lane reads B[k = (lane>>5)*8 + j][n = lane&31]
//  C/D:    col = lane&31, row = (reg&3) + 8*(reg>>2) + 4*(lane>>5)

#define LOG2E 1.4426950408889634f

static __device__ __forceinline__ ushortT f2b(float f) {
    union { float f; uintT u; } v; v.f = f;
    uintT u = v.u;
    u += 0x7fffu + ((u >> 16) & 1u);     // round-to-nearest-even
    return (ushortT)(u >> 16);
}
static __device__ __forceinline__ uintT pack2(float a, float b) {
    return (uintT)f2b(a) | ((uintT)f2b(b) << 16);
}
// truncating bf16 pack of two fp32 in ONE v_perm_b32 (low16=a, high16=b)
static __device__ __forceinline__ uintT pack2t(float a, float b) {
    union { float f; uintT u; } x0, x1; x0.f = a; x1.f = b;
    return __builtin_amdgcn_perm(x1.u, x0.u, 0x07060302u);
}
static __device__ __forceinline__ float blo(uintT u) {
    union { uintT u; float f; } v; v.u = u << 16; return v.f;
}
static __device__ __forceinline__ float bhi(uintT u) {
    union { uintT u; float f; } v; v.u = u & 0xffff0000u; return v.f;
}
static __device__ __forceinline__ f32x16 zero16() {
    f32x16 z;
    #pragma unroll
    for (int i = 0; i < 16; ++i) z[i] = 0.f;
    return z;
}

#define NQB 16
#define NKB 32

// ---------------------------------------------------------------------------
// Fused prep: x fp32->bf16 (blocks 0..2047), Wqkv transpose (2048..2815),
// Wproj transpose (2816..3071). ROUND-19: REVERTED to this xb path -- R7/R8
// proved qkv-reads-x-directly costs ~6us (2x A-stage bytes + pack2 on the
// staging critical path + 192MB x re-reads). This exact config benched 135.4.
// ---------------------------------------------------------------------------
__global__ __launch_bounds__(256) void prep_kernel(
    const float* __restrict__ x, ushortT* __restrict__ xb,
    const float* __restrict__ Wq, ushortT* __restrict__ Wqt,
    const float* __restrict__ Wp, ushortT* __restrict__ Wpt) {
    const int bid = blockIdx.x, t = threadIdx.x;
    __shared__ float tile[32][33];
    if (bid < 2048) {
        int i = (bid * 256 + t) * 4;
        float4 v = *(const float4*)(x + i);
        uint2 o; o.x = pack2(v.x, v.y); o.y = pack2(v.z, v.w);
        *(uint2*)(xb + i) = o;
        return;
    }
    const float* W; ushortT* Wt; int C, c0, r0;
    if (bid < 2816) {
        const int b = bid - 2048;
        W = Wq; Wt = Wqt; C = 1536;
        c0 = (b % 48) * 32; r0 = (b / 48) * 32;
    } else {
        const int b = bid - 2816;
        W = Wp; Wt = Wpt; C = 512;
        c0 = (b & 15) * 32; r0 = (b >> 4) * 32;
    }
    const int tx = t & 31, ty = t >> 5;
    #pragma unroll
    for (int i = 0; i < 4; ++i)
        tile[ty + 8 * i][tx] = W[(size_t)(r0 + ty + 8 * i) * C + c0 + tx];
    __syncthreads();
    #pragma unroll
    for (int i = 0; i < 4; ++i) {
        int rr = ty + 8 * i;
        Wt[(size_t)(c0 + rr) * 512 + r0 + tx] = f2b(tile[tx][rr]);
    }
}

// ---------------------------------------------------------------------------
// QKV GEMM (bf16 MFMA): 128x64 tiles, grid (24,32) = 768 blocks = 3/CU.
// Wave w owns rows [32w,32w+32), 2 col-tiles of 32. Double-buffered LDS.
//  -> qb (scaled 0.125*LOG2E), kbuf [bh][L][64], vt [bh][kb][d][64key]
//  fp32 block means qm (scaled 0.125), km. Cos fused in epilogue (R14).
// ---------------------------------------------------------------------------
__global__ __launch_bounds__(256) void qkv_gemm_kernel(
    const ushortT* __restrict__ xb, const ushortT* __restrict__ wt,
    const float* __restrict__ bias,
    ushortT* __restrict__ qb, ushortT* __restrict__ kbuf, ushortT* __restrict__ vt,
    float* __restrict__ qm, float* __restrict__ km,
    float* __restrict__ qs, float* __restrict__ ks) {
    __shared__ __align__(16) ushortT As[2][128 * 40];
    __shared__ __align__(16) ushortT Bs[2][64 * 40];
    __shared__ float sumbuf[4][64];
    __shared__ float meanS[2][64];
    __shared__ float wminS[4];
    const int t = threadIdx.x;
    const int l = t & 63, w = t >> 6;
    const int lm = l & 31, lh = l >> 5;
    const int rowbase = blockIdx.y * 128;
    const int colbase = blockIdx.x * 64;

    f32x16 acc[2];
    acc[0] = zero16(); acc[1] = zero16();

    // A loader: thread -> row t>>1 (0..127), k-half t&1 (16 elems)
    const int r = t >> 1, half = t & 1;
    const ushortT* Ag = xb + (size_t)(rowbase + r) * 512 + half * 16;
    const int soA = r * 40 + half * 16;
    // B loader: thread -> row t>>2 (0..63), k-quarter t&3 (8 elems)
    const int rb = t >> 2, q4 = t & 3;
    const ushortT* Bg = wt + (size_t)(colbase + rb) * 512 + q4 * 8;
    const int soB = rb * 40 + q4 * 8;

    uint4 a0, a1, b0;
    a0 = *(const uint4*)(Ag); a1 = *(const uint4*)(Ag + 8);
    b0 = *(const uint4*)(Bg);
    *(uint4*)(&As[0][soA]) = a0; *(uint4*)(&As[0][soA] + 8) = a1;
    *(uint4*)(&Bs[0][soB]) = b0;

    for (int k0 = 0; k0 < 512; k0 += 32) {
        const int cur = (k0 >> 5) & 1;
        __syncthreads();
        if (k0 < 480) {
            a0 = *(const uint4*)(Ag + k0 + 32); a1 = *(const uint4*)(Ag + k0 + 40);
            b0 = *(const uint4*)(Bg + k0 + 32);
        }
        #pragma unroll
        for (int ks2 = 0; ks2 < 2; ++ks2) {
            const int ko = 16 * ks2 + 8 * lh;
            short8 af  = *(const short8*)(&As[cur][(32 * w + lm) * 40 + ko]);
            short8 b_0 = *(const short8*)(&Bs[cur][lm * 40 + ko]);
            short8 b_1 = *(const short8*)(&Bs[cur][(32 + lm) * 40 + ko]);
            acc[0] = MFMA32(af, b_0, acc[0]);
            acc[1] = MFMA32(af, b_1, acc[1]);
        }
        if (k0 < 480) {
            const int nxt = cur ^ 1;
            *(uint4*)(&As[nxt][soA]) = a0; *(uint4*)(&As[nxt][soA] + 8) = a1;
            *(uint4*)(&Bs[nxt][soB]) = b0;
        }
    }

    // epilogue: 64-col tile = exactly one (which, head)
    const int which = blockIdx.x >> 3;            // 0=q 1=k 2=v
    const int h = blockIdx.x & 7;
    const int by = blockIdx.y;
    const int b = by >> 4;
    const size_t hb = (size_t)(b * 8 + h);
    float bias2[2];
    #pragma unroll
    for (int nt = 0; nt < 2; ++nt) bias2[nt] = bias[colbase + 32 * nt + lm];
    float msum[2] = {0.f, 0.f};
    #pragma unroll
    for (int nt = 0; nt < 2; ++nt) {
        const int dd = 32 * nt + lm;
        #pragma unroll
        for (int rg = 0; rg < 16; ++rg) {
            const int row_local = 32 * w + (rg & 3) + 8 * (rg >> 2) + 4 * lh;
            const int ll = (rowbase + row_local) & 2047;
            float val = acc[nt][rg] + bias2[nt];
            if (which == 0) {
                val *= 0.125f;
                msum[nt] += val;
                qb[(hb * 2048 + ll) * 64 + dd] = f2b(val * LOG2E);
            } else if (which == 1) {
                msum[nt] += val;
                kbuf[(hb * 2048 + ll) * 64 + dd] = f2b(val);
            } else {
                vt[hb * 131072 + (size_t)(ll >> 6) * 4096 + dd * 64 + (ll & 63)] = f2b(val);
            }
            acc[nt][rg] = val;   // keep for fused cosine
        }
    }
    if (which == 2) return;
    #pragma unroll
    for (int nt = 0; nt < 2; ++nt) {
        float s = msum[nt] + __shfl_xor(msum[nt], 32);   // full 32-row col sum
        if (l < 32) sumbuf[w][32 * nt + lm] = s;
    }
    __syncthreads();
    // block means -> global + LDS (for cosine)
    if (which == 0) {
        if (t < 64) {
            const int qbi = by & 15;
            const float m =
                (sumbuf[0][t] + sumbuf[1][t] + sumbuf[2][t] + sumbuf[3][t]) * (1.0f / 128.0f);
            qm[(hb * 16 + qbi) * 64 + t] = m;
            meanS[0][t] = m;
        }
    } else {
        if (t < 128) {
            const int d = t & 63, pair = t >> 6;      // pair 0: waves 0-1, 1: waves 2-3
            const int kbi = 2 * (by & 15) + pair;
            const float m =
                (sumbuf[2 * pair][d] + sumbuf[2 * pair + 1][d]) * (1.0f / 64.0f);
            km[(hb * 32 + kbi) * 64 + d] = m;
            meanS[pair][d] = m;
        }
    }
    __syncthreads();
    // fused min-cosine-to-mean: thread holds cols {lm, 32+lm} of 16 rows
    {
        const int mrow = (which == 0) ? 0 : (w >> 1);
        const float mv0 = meanS[mrow][lm], mv1 = meanS[mrow][32 + lm];
        float mn2 = mv0 * mv0 + mv1 * mv1;
        #pragma unroll
        for (int off = 1; off < 32; off <<= 1) mn2 += __shfl_xor(mn2, off);
        const float mnorm = sqrtf(mn2);
        float cmin = 1e30f;
        #pragma unroll
        for (int rg = 0; rg < 16; ++rg) {
            float dp = acc[0][rg] * mv0 + acc[1][rg] * mv1;
            float nn = acc[0][rg] * acc[0][rg] + acc[1][rg] * acc[1][rg];
            #pragma unroll
            for (int off = 1; off < 32; off <<= 1) {
                dp += __shfl_xor(dp, off);
                nn += __shfl_xor(nn, off);
            }
            const float cosv = dp / ((sqrtf(nn) + 1e-6f) * (mnorm + 1e-6f));
            cmin = fminf(cmin, cosv);
        }
        cmin = fminf(cmin, __shfl_xor(cmin, 32));
        if (l == 0) wminS[w] = cmin;
    }
    __syncthreads();
    if (t == 0) {
        if (which == 0) {
            qs[hb * 16 + (by & 15)] =
                fminf(fminf(wminS[0], wminS[1]), fminf(wminS[2], wminS[3]));
        } else {
            ks[hb * 32 + 2 * (by & 15)]     = fminf(wminS[0], wminS[1]);
            ks[hb * 32 + 2 * (by & 15) + 1] = fminf(wminS[2], wminS[3]);
        }
    }
}

// ---------------------------------------------------------------------------
// Flash attention, bf16 MFMA, S^T form, exp2 softmax, inline mask (R14).
// KVBLK=128 (2 K-blocks/iter), 70KB LDS -> 2 blocks/CU co-residency,
// launch_bounds(512,2), flat body. This exact kernel benched 135.4 total.
// 512 threads = 8 waves = 2 q-col groups (qc) x 4 key quarters (kq).
// Epilogue: 4 key-quarter partials reduced in LDS, divide by l, write ob.
// ---------------------------------------------------------------------------
#define KS_SH (128 * 72)
#define VS_SH (64 * 136)
__global__ __launch_bounds__(512, 2) void attn_kernel(
    const ushortT* __restrict__ qb, const ushortT* __restrict__ kbuf,
    const ushortT* __restrict__ vt,
    const float* __restrict__ qm, const float* __restrict__ km,
    const float* __restrict__ qs, const float* __restrict__ ks,
    ushortT* __restrict__ ob) {
    // main-loop LDS: Ks[2][128key][72], Vs[2][64d][136key-pad] = 70 KB
    // epilogue aliases the same region: ox uint4[6][8][64] (48K) + lx (1.5K)
    __shared__ __align__(16) ushortT smem[2 * KS_SH + 2 * VS_SH];
    __shared__ int klist[33];
    __shared__ float qmS[64];
    __shared__ float pnS[32];
    ushortT (*Ks)[KS_SH] = (ushortT(*)[KS_SH])smem;
    ushortT (*Vs)[VS_SH] = (ushortT(*)[VS_SH])(smem + 2 * KS_SH);

    const int t = threadIdx.x;
    const int l = t & 63, w = t >> 6;
    const int lm = l & 31, lh = l >> 5;
    const int qc = w >> 2, kq = w & 3;        // q 64-group, key 32-quarter
    const int bh = blockIdx.x, qt = blockIdx.y;

    if (t < 64) qmS[t] = qm[((size_t)bh * 16 + qt) * 64 + t];

    // Q B-frags straight from global: wave qc owns q rows [64qc, 64qc+64)
    const ushortT* qg = qb + ((size_t)bh * 2048 + qt * 128) * 64;
    short8 qf[4][2];
    #pragma unroll
    for (int qh = 0; qh < 2; ++qh)
        #pragma unroll
        for (int ksd = 0; ksd < 4; ++ksd)
            qf[ksd][qh] = *(const short8*)(qg + (64 * qc + 32 * qh + lm) * 64 + 16 * ksd + 8 * lh);
    __syncthreads();   // qmS visible

    // inline mask row (wave 0, lanes < 32): pooled softmax + CDF keep
    if (w == 0 && l < 32) {
        const float* kmr = km + ((size_t)bh * 32 + l) * 64;
        float dot = 0.f;
        #pragma unroll
        for (int d = 0; d < 64; ++d) dot += qmS[d] * kmr[d];
        float mx = dot;
        #pragma unroll
        for (int off = 1; off < 32; off <<= 1) mx = fmaxf(mx, __shfl_xor(mx, off));
        const float e = expf(dot - mx);
        float sum = e;
        #pragma unroll
        for (int off = 1; off < 32; off <<= 1) sum += __shfl_xor(sum, off);
        const float pn = e * (1.0f / sum);
        pnS[l] = pn;
        float before = 0.f;
        #pragma unroll
        for (int j = 0; j < 32; ++j) {
            const float pj = pnS[j];
            if (pj > pn || (pj == pn && j < l)) before += pj;
        }
        const bool qfb = !(qs[bh * 16 + qt] > 0.6f);
        const bool kfb = !(ks[bh * 32 + l] > 0.6f);
        const bool keep = (before < 0.98f) || qfb || kfb;
        unsigned long long bal = __ballot(keep);
        if (keep) {
            const int rank = __popcll(bal & ((1ULL << l) - 1ULL));
            klist[rank] = l;
        }
        if (l == 0) klist[32] = __popcll(bal);
    }
    __syncthreads();   // klist visible

    const int cnt = klist[32];
    const int nIter = (cnt + 1) >> 1;

    // staging: thread -> tile (0,1: K kh / 2,3: V kh), 64 rows x 64 cols each,
    // 4 uint4 per thread
    const int tile = t >> 7, tt = t & 127;
    const int isV = tile >> 1, skh = tile & 1;
    const int srow = tt >> 1, shalf = (tt & 1) * 32;
    const ushortT* gsrc = (isV ? vt : kbuf) + (size_t)bh * 131072;
    const int goff = srow * 64 + shalf;   // K: [key][d] ; V(vt): [d][key]
    const int soff = isV ? (srow * 136 + skh * 64 + shalf)
                         : ((skh * 64 + srow) * 72 + shalf);
    ushortT* sd0 = (isV ? &Vs[0][soff] : &Ks[0][soff]);
    ushortT* sd1 = (isV ? &Vs[1][soff] : &Ks[1][soff]);

    f32x16 oacc[2][2];
    oacc[0][0] = zero16(); oacc[1][0] = zero16();
    oacc[0][1] = zero16(); oacc[1][1] = zero16();
    float l_i[2] = {0.f, 0.f};

    uint4 st0, st1, st2, st3;
    {   // prologue: stage iteration 0
        int kidx = skh; if (kidx >= cnt) kidx = cnt - 1;
        const ushortT* g = gsrc + (size_t)klist[kidx] * 4096 + goff;
        st0 = *(const uint4*)(g);      st1 = *(const uint4*)(g + 8);
        st2 = *(const uint4*)(g + 16); st3 = *(const uint4*)(g + 24);
        *(uint4*)(sd0)      = st0; *(uint4*)(sd0 + 8)  = st1;
        *(uint4*)(sd0 + 16) = st2; *(uint4*)(sd0 + 24) = st3;
    }

    for (int i = 0; i < nIter; ++i) {
        const int cur = i & 1;
        __syncthreads();
        if (i + 1 < nIter) {
            int kidx = 2 * (i + 1) + skh; if (kidx >= cnt) kidx = cnt - 1;
            const ushortT* g = gsrc + (size_t)klist[kidx] * 4096 + goff;
            st0 = *(const uint4*)(g);      st1 = *(const uint4*)(g + 8);
            st2 = *(const uint4*)(g + 16); st3 = *(const uint4*)(g + 24);
        }
        // this wave's 32 keys live in key-block half kq>>1 of this iteration
        const float mf = (2 * i + (kq >> 1) < cnt) ? 1.f : 0.f;
        // S^T = K * Q^T  (S already in log2e units)
        f32x16 sacc[2];
        sacc[0] = zero16(); sacc[1] = zero16();
        #pragma unroll
        for (int ksd = 0; ksd < 4; ++ksd) {
            const int ko = 16 * ksd + 8 * lh;
            short8 kf = *(const short8*)(&Ks[cur][(32 * kq + lm) * 72 + ko]);
            sacc[0] = MFMA32(kf, qf[ksd][0], sacc[0]);
            sacc[1] = MFMA32(kf, qf[ksd][1], sacc[1]);
        }
        // p = exp2(s) * mf (mf==1 except odd-cnt tail)
        uintT uu[2][4][2];   // [qh][rb][pair]
        #pragma unroll
        for (int qh = 0; qh < 2; ++qh) {
            float psum0 = 0.f, psum1 = 0.f;
            #pragma unroll
            for (int rp = 0; rp < 8; ++rp) {
                const float e0 = __builtin_amdgcn_exp2f(sacc[qh][2 * rp]) * mf;
                const float e1 = __builtin_amdgcn_exp2f(sacc[qh][2 * rp + 1]) * mf;
                psum0 += e0; psum1 += e1;
                uu[qh][rp >> 1][rp & 1] = pack2t(e0, e1);
            }
            float psum = psum0 + psum1;
            psum += __shfl_xor(psum, 32);
            l_i[qh] += psum;
        }
        // O^T += V^T * P^T ; P^T B-frag via lane pair-exchange
        #pragma unroll
        for (int ksk = 0; ksk < 2; ++ksk) {
            const int vko = 32 * kq + 16 * ksk + 8 * lh;
            short8 vf0 = *(const short8*)(&Vs[cur][lm * 136 + vko]);
            short8 vf1 = *(const short8*)(&Vs[cur][(32 + lm) * 136 + vko]);
            #pragma unroll
            for (int qh = 0; qh < 2; ++qh) {
                const uintT kA = lh ? uu[qh][2 * ksk + 1][0] : uu[qh][2 * ksk][0];
                const uintT kB = lh ? uu[qh][2 * ksk + 1][1] : uu[qh][2 * ksk][1];
                const uintT sA = lh ? uu[qh][2 * ksk][0] : uu[qh][2 * ksk + 1][0];
                const uintT sB = lh ? uu[qh][2 * ksk][1] : uu[qh][2 * ksk + 1][1];
                const uintT rA = (uintT)__shfl_xor((int)sA, 32);
                const uintT rB = (uintT)__shfl_xor((int)sB, 32);
                union { uintT u[4]; short8 v; } cv;
                if (lh == 0) { cv.u[0] = kA; cv.u[1] = kB; cv.u[2] = rA; cv.u[3] = rB; }
                else         { cv.u[0] = rA; cv.u[1] = rB; cv.u[2] = kA; cv.u[3] = kB; }
                oacc[0][qh] = MFMA32(vf0, cv.v, oacc[0][qh]);
                oacc[1][qh] = MFMA32(vf1, cv.v, oacc[1][qh]);
            }
        }
        if (i + 1 < nIter) {
            ushortT* sd = (cur ^ 1) ? sd1 : sd0;
            *(uint4*)(sd)      = st0; *(uint4*)(sd + 8)  = st1;
            *(uint4*)(sd + 16) = st2; *(uint4*)(sd + 24) = st3;
        }
    }

    // ---- cross-kq reduction in LDS (aliases dead K/V buffers) ----
    uint4* ox = (uint4*)smem;                          // [6 wslot][8 reg-grp][64 lane]
    float* lx = (float*)((char*)smem + 49152);         // [6 wslot][2 qh][32 lm]
    __syncthreads();
    if (kq != 0) {
        const int wslot = qc * 3 + (kq - 1);
        #pragma unroll
        for (int dt = 0; dt < 2; ++dt)
            #pragma unroll
            for (int qh = 0; qh < 2; ++qh)
                #pragma unroll
                for (int g2 = 0; g2 < 2; ++g2) {
                    uint4 u;
                    u.x = pack2(oacc[dt][qh][8 * g2 + 0], oacc[dt][qh][8 * g2 + 1]);
                    u.y = pack2(oacc[dt][qh][8 * g2 + 2], oacc[dt][qh][8 * g2 + 3]);
                    u.z = pack2(oacc[dt][qh][8 * g2 + 4], oacc[dt][qh][8 * g2 + 5]);
                    u.w = pack2(oacc[dt][qh][8 * g2 + 6], oacc[dt][qh][8 * g2 + 7]);
                    ox[(wslot * 8 + (dt * 4 + qh * 2 + g2)) * 64 + l] = u;
                }
        if (lh == 0) {
            lx[(wslot * 2 + 0) * 32 + lm] = l_i[0];
            lx[(wslot * 2 + 1) * 32 + lm] = l_i[1];
        }
    }
    __syncthreads();
    if (kq == 0) {
        float lt[2] = {l_i[0], l_i[1]};
        #pragma unroll
        for (int p = 0; p < 3; ++p) {
            const int ws2 = qc * 3 + p;
            lt[0] += lx[(ws2 * 2 + 0) * 32 + lm];
            lt[1] += lx[(ws2 * 2 + 1) * 32 + lm];
            #pragma unroll
            for (int dt = 0; dt < 2; ++dt)
                #pragma unroll
                for (int qh = 0; qh < 2; ++qh)
                    #pragma unroll
                    for (int g2 = 0; g2 < 2; ++g2) {
                        uint4 u = ox[(ws2 * 8 + (dt * 4 + qh * 2 + g2)) * 64 + l];
                        oacc[dt][qh][8 * g2 + 0] += blo(u.x);
                        oacc[dt][qh][8 * g2 + 1] += bhi(u.x);
                        oacc[dt][qh][8 * g2 + 2] += blo(u.y);
                        oacc[dt][qh][8 * g2 + 3] += bhi(u.y);
                        oacc[dt][qh][8 * g2 + 4] += blo(u.z);
                        oacc[dt][qh][8 * g2 + 5] += bhi(u.z);
                        oacc[dt][qh][8 * g2 + 6] += blo(u.w);
                        oacc[dt][qh][8 * g2 + 7] += bhi(u.w);
                    }
        }
        #pragma unroll
        for (int qh = 0; qh < 2; ++qh) {
            const float inv = 1.0f / lt[qh];
            const int token = qt * 128 + qc * 64 + 32 * qh + lm;
            ushortT* orow = ob + ((size_t)bh * 2048 + token) * 64;
            #pragma unroll
            for (int dt = 0; dt < 2; ++dt)
                #pragma unroll
                for (int rp = 0; rp < 8; ++rp) {
                    const int d0 = 32 * dt + 8 * (rp >> 1) + 4 * lh + 2 * (rp & 1);
                    *(uintT*)(orow + d0) =
                        pack2(oacc[dt][qh][2 * rp] * inv, oacc[dt][qh][2 * rp + 1] * inv);
                }
        }
    }
}

// ---------------------------------------------------------------------------
// Proj GEMM: 64x64 tiles, grid (8,64) = 512 blocks = 2 waves/SIMD.
// ob (gathered [4096,512] bf16) @ Wprojt^T + bias -> out fp32.
// ---------------------------------------------------------------------------
__global__ __launch_bounds__(256) void proj_gemm_kernel(
    const ushortT* __restrict__ ob, const ushortT* __restrict__ wpt,
    const float* __restrict__ bias, float* __restrict__ out) {
    __shared__ __align__(16) ushortT As[2][64 * 40];
    __shared__ __align__(16) ushortT Bs[2][64 * 40];
    const int t = threadIdx.x;
    const int l = t & 63, w = t >> 6;
    const int lm = l & 31, lh = l >> 5;
    const int rh = w & 1, ch = w >> 1;            // wave -> 32-row half, 32-col half
    const int rowbase = blockIdx.y * 64;
    const int colbase = blockIdx.x * 64;

    f32x16 acc = zero16();

    const int r = t >> 2, q4 = t & 3;             // row 0..63, k-quarter (8 elems)
    const int token = rowbase + r;
    const int b2 = token >> 11, lt = token & 2047;
    const int so = r * 40 + q4 * 8;
    const ushortT* obbase = ob + ((size_t)(b2 * 8) * 2048 + lt) * 64 + q4 * 8;
    const ushortT* Bg = wpt + (size_t)(colbase + r) * 512 + q4 * 8;

    uint4 a0, b0;
    a0 = *(const uint4*)(obbase);
    b0 = *(const uint4*)(Bg);
    *(uint4*)(&As[0][so]) = a0;
    *(uint4*)(&Bs[0][so]) = b0;

    for (int k0 = 0; k0 < 512; k0 += 32) {
        const int cur = (k0 >> 5) & 1;
        __syncthreads();
        if (k0 < 480) {
            const int kn = k0 + 32;
            const ushortT* Ag = obbase + (size_t)(kn >> 6) * 131072 + (kn & 63);
            a0 = *(const uint4*)(Ag);
            b0 = *(const uint4*)(Bg + kn);
        }
        #pragma unroll
        for (int ks2 = 0; ks2 < 2; ++ks2) {
            const int ko = 16 * ks2 + 8 * lh;
            short8 af = *(const short8*)(&As[cur][(32 * rh + lm) * 40 + ko]);
            short8 bf = *(const short8*)(&Bs[cur][(32 * ch + lm) * 40 + ko]);
            acc = MFMA32(af, bf, acc);
        }
        if (k0 < 480) {
            const int nxt = cur ^ 1;
            *(uint4*)(&As[nxt][so]) = a0;
            *(uint4*)(&Bs[nxt][so]) = b0;
        }
    }
    const int c = colbase + 32 * ch + lm;
    const float bb = bias[c];
    #pragma unroll
    for (int rg = 0; rg < 16; ++rg) {
        const int row_local = 32 * rh + (rg & 3) + 8 * (rg >> 2) + 4 * lh;
        out[(size_t)(rowbase + row_local) * 512 + c] = acc[rg] + bb;
    }
}

// ---------------------------------------------------------------------------
extern "C" void kernel_launch(void* const* d_in, const int* in_sizes, int n_in,
                              void* d_out, int out_size, void* d_ws, size_t ws_size,
                              hipStream_t stream) {
    const float* x     = (const float*)d_in[0];
    const float* Wqkv  = (const float*)d_in[1];
    const float* bqkv  = (const float*)d_in[2];
    const float* Wproj = (const float*)d_in[3];
    const float* bproj = (const float*)d_in[4];
    float* out = (float*)d_out;

    char* w = (char*)d_ws;
    ushortT* xb     = (ushortT*)(w);                    // 4 MB
    ushortT* wqkvt  = (ushortT*)(w + 4194304);          // 1.5 MB
    ushortT* wprojt = (ushortT*)(w + 5767168);          // 0.5 MB
    ushortT* qb     = (ushortT*)(w + 6291456);          // 4 MB (scaled 0.125*log2e)
    ushortT* kbuf   = (ushortT*)(w + 10485760);         // 4 MB
    ushortT* vt     = (ushortT*)(w + 14680064);         // 4 MB (transposed per k-block)
    ushortT* ob     = (ushortT*)(w + 18874368);         // 4 MB (final attention output)
    float*   qm     = (float*)(w + 23068672);           // 64 KB
    float*   km     = (float*)(w + 23134208);           // 128 KB
    float*   qs     = (float*)(w + 36406272);           // 1 KB
    float*   ks     = (float*)(w + 36407296);           // 2 KB

    prep_kernel<<<3072, 256, 0, stream>>>(x, xb, Wqkv, wqkvt, Wproj, wprojt);
    qkv_gemm_kernel<<<dim3(24, 32), 256, 0, stream>>>(xb, wqkvt, bqkv, qb, kbuf, vt,
                                                      qm, km, qs, ks);
    attn_kernel<<<dim3(16, 16), 512, 0, stream>>>(qb, kbuf, vt, qm, km, qs, ks, ob);
    proj_gemm_kernel<<<dim3(8, 64), 256, 0, stream>>>(ob, wprojt, bproj, out);
}

// Round 10
// 127.325 us; speedup vs baseline: 1.1100x; 1.0572x over previous
//
#include <hip/hip_runtime.h>
#include <math.h>

typedef unsigned short ushortT;
typedef unsigned int uintT;
typedef __attribute__((ext_vector_type(8))) short short8;
typedef __attribute__((ext_vector_type(16))) float f32x16;
#define MFMA32(a, b, c) __builtin_amdgcn_mfma_f32_32x32x16_bf16((a), (b), (c), 0, 0, 0)

// MFMA 32x32x16 layouts (gfx950, HW-verified m74/m101/m120):
//  A-frag: lane reads A[m = lane&31][k = (lane>>5)*8 + j], j=0..7
//  B-frag: lane reads B[k = (lane>>5)*8 + j][n = lane&31]
//  C/D:    col = lane&31, row = (reg&3) + 8*(reg>>2) + 4*(lane>>5)

#define LOG2E 1.4426950408889634f

static __device__ __forceinline__ ushortT f2b(float f) {
    union { float f; uintT u; } v; v.f = f;
    uintT u = v.u;
    u += 0x7fffu + ((u >> 16) & 1u);     // round-to-nearest-even
    return (ushortT)(u >> 16);
}
static __device__ __forceinline__ uintT pack2(float a, float b) {
    return (uintT)f2b(a) | ((uintT)f2b(b) << 16);
}
// truncating bf16 pack of two fp32 in ONE v_perm_b32 (low16=a, high16=b)
static __device__ __forceinline__ uintT pack2t(float a, float b) {
    union { float f; uintT u; } x0, x1; x0.f = a; x1.f = b;
    return __builtin_amdgcn_perm(x1.u, x0.u, 0x07060302u);
}
static __device__ __forceinline__ float blo(uintT u) {
    union { uintT u; float f; } v; v.u = u << 16; return v.f;
}
static __device__ __forceinline__ float bhi(uintT u) {
    union { uintT u; float f; } v; v.u = u & 0xffff0000u; return v.f;
}
static __device__ __forceinline__ f32x16 zero16() {
    f32x16 z;
    #pragma unroll
    for (int i = 0; i < 16; ++i) z[i] = 0.f;
    return z;
}

#define NQB 16
#define NKB 32

// ---------------------------------------------------------------------------
// Fused prep: x fp32->bf16 (blocks 0..2047), Wqkv transpose (2048..2815),
// Wproj transpose (2816..3071).
// ---------------------------------------------------------------------------
__global__ __launch_bounds__(256) void prep_kernel(
    const float* __restrict__ x, ushortT* __restrict__ xb,
    const float* __restrict__ Wq, ushortT* __restrict__ Wqt,
    const float* __restrict__ Wp, ushortT* __restrict__ Wpt) {
    const int bid = blockIdx.x, t = threadIdx.x;
    __shared__ float tile[32][33];
    if (bid < 2048) {
        int i = (bid * 256 + t) * 4;
        float4 v = *(const float4*)(x + i);
        uint2 o; o.x = pack2(v.x, v.y); o.y = pack2(v.z, v.w);
        *(uint2*)(xb + i) = o;
        return;
    }
    const float* W; ushortT* Wt; int C, c0, r0;
    if (bid < 2816) {
        const int b = bid - 2048;
        W = Wq; Wt = Wqt; C = 1536;
        c0 = (b % 48) * 32; r0 = (b / 48) * 32;
    } else {
        const int b = bid - 2816;
        W = Wp; Wt = Wpt; C = 512;
        c0 = (b & 15) * 32; r0 = (b >> 4) * 32;
    }
    const int tx = t & 31, ty = t >> 5;
    #pragma unroll
    for (int i = 0; i < 4; ++i)
        tile[ty + 8 * i][tx] = W[(size_t)(r0 + ty + 8 * i) * C + c0 + tx];
    __syncthreads();
    #pragma unroll
    for (int i = 0; i < 4; ++i) {
        int rr = ty + 8 * i;
        Wt[(size_t)(c0 + rr) * 512 + r0 + tx] = f2b(tile[tx][rr]);
    }
}

// ---------------------------------------------------------------------------
// QKV GEMM (bf16 MFMA): 128x64 tiles, grid (24,32) = 768 blocks = 3/CU.
// Cos fused in epilogue (R14). ROUND-20: K and V are written in
// MFMA-FRAGMENT-LINEAR layout: [bh][kblock][frag(8)][lane(64)][8 bf16],
// so attn A-frag loads are single coalesced 1KB wave transactions.
//  K frag  = (kh = key32-half, ksd = d16-slice): lane=(key&31)+32*((d>>3)&1), j=d&7
//  V frag  = (dt = d32-half, ksl = key16-slice): lane=(d&31)+32*((key>>3)&1), j=key&7
// ---------------------------------------------------------------------------
__global__ __launch_bounds__(256) void qkv_gemm_kernel(
    const ushortT* __restrict__ xb, const ushortT* __restrict__ wt,
    const float* __restrict__ bias,
    ushortT* __restrict__ qb, ushortT* __restrict__ kfrag, ushortT* __restrict__ vfrag,
    float* __restrict__ qm, float* __restrict__ km,
    float* __restrict__ qs, float* __restrict__ ks) {
    __shared__ __align__(16) ushortT As[2][128 * 40];
    __shared__ __align__(16) ushortT Bs[2][64 * 40];
    __shared__ float sumbuf[4][64];
    __shared__ float meanS[2][64];
    __shared__ float wminS[4];
    const int t = threadIdx.x;
    const int l = t & 63, w = t >> 6;
    const int lm = l & 31, lh = l >> 5;
    const int rowbase = blockIdx.y * 128;
    const int colbase = blockIdx.x * 64;

    f32x16 acc[2];
    acc[0] = zero16(); acc[1] = zero16();

    // A loader: thread -> row t>>1 (0..127), k-half t&1 (16 elems)
    const int r = t >> 1, half = t & 1;
    const ushortT* Ag = xb + (size_t)(rowbase + r) * 512 + half * 16;
    const int soA = r * 40 + half * 16;
    // B loader: thread -> row t>>2 (0..63), k-quarter t&3 (8 elems)
    const int rb = t >> 2, q4 = t & 3;
    const ushortT* Bg = wt + (size_t)(colbase + rb) * 512 + q4 * 8;
    const int soB = rb * 40 + q4 * 8;

    uint4 a0, a1, b0;
    a0 = *(const uint4*)(Ag); a1 = *(const uint4*)(Ag + 8);
    b0 = *(const uint4*)(Bg);
    *(uint4*)(&As[0][soA]) = a0; *(uint4*)(&As[0][soA] + 8) = a1;
    *(uint4*)(&Bs[0][soB]) = b0;

    for (int k0 = 0; k0 < 512; k0 += 32) {
        const int cur = (k0 >> 5) & 1;
        __syncthreads();
        if (k0 < 480) {
            a0 = *(const uint4*)(Ag + k0 + 32); a1 = *(const uint4*)(Ag + k0 + 40);
            b0 = *(const uint4*)(Bg + k0 + 32);
        }
        #pragma unroll
        for (int ks2 = 0; ks2 < 2; ++ks2) {
            const int ko = 16 * ks2 + 8 * lh;
            short8 af  = *(const short8*)(&As[cur][(32 * w + lm) * 40 + ko]);
            short8 b_0 = *(const short8*)(&Bs[cur][lm * 40 + ko]);
            short8 b_1 = *(const short8*)(&Bs[cur][(32 + lm) * 40 + ko]);
            acc[0] = MFMA32(af, b_0, acc[0]);
            acc[1] = MFMA32(af, b_1, acc[1]);
        }
        if (k0 < 480) {
            const int nxt = cur ^ 1;
            *(uint4*)(&As[nxt][soA]) = a0; *(uint4*)(&As[nxt][soA] + 8) = a1;
            *(uint4*)(&Bs[nxt][soB]) = b0;
        }
    }

    // epilogue: 64-col tile = exactly one (which, head)
    const int which = blockIdx.x >> 3;            // 0=q 1=k 2=v
    const int h = blockIdx.x & 7;
    const int by = blockIdx.y;
    const int b = by >> 4;
    const size_t hb = (size_t)(b * 8 + h);
    float bias2[2];
    #pragma unroll
    for (int nt = 0; nt < 2; ++nt) bias2[nt] = bias[colbase + 32 * nt + lm];
    float msum[2] = {0.f, 0.f};
    #pragma unroll
    for (int nt = 0; nt < 2; ++nt) {
        const int dd = 32 * nt + lm;
        #pragma unroll
        for (int rg = 0; rg < 16; ++rg) {
            const int row_local = 32 * w + (rg & 3) + 8 * (rg >> 2) + 4 * lh;
            const int ll = (rowbase + row_local) & 2047;
            float val = acc[nt][rg] + bias2[nt];
            if (which == 0) {
                val *= 0.125f;
                msum[nt] += val;
                qb[(hb * 2048 + ll) * 64 + dd] = f2b(val * LOG2E);
            } else if (which == 1) {
                msum[nt] += val;
                const int koff = (((ll >> 6) * 8 + ((ll >> 5) & 1) * 4 + (dd >> 4)) << 9)
                               + (((ll & 31) + 32 * ((dd >> 3) & 1)) << 3) + (dd & 7);
                kfrag[hb * 131072 + koff] = f2b(val);
            } else {
                const int voff = (((ll >> 6) * 8 + (dd >> 5) * 4 + ((ll >> 4) & 3)) << 9)
                               + (((dd & 31) + 32 * ((ll >> 3) & 1)) << 3) + (ll & 7);
                vfrag[hb * 131072 + voff] = f2b(val);
            }
            acc[nt][rg] = val;   // keep for fused cosine
        }
    }
    if (which == 2) return;
    #pragma unroll
    for (int nt = 0; nt < 2; ++nt) {
        float s = msum[nt] + __shfl_xor(msum[nt], 32);   // full 32-row col sum
        if (l < 32) sumbuf[w][32 * nt + lm] = s;
    }
    __syncthreads();
    // block means -> global + LDS (for cosine)
    if (which == 0) {
        if (t < 64) {
            const int qbi = by & 15;
            const float m =
                (sumbuf[0][t] + sumbuf[1][t] + sumbuf[2][t] + sumbuf[3][t]) * (1.0f / 128.0f);
            qm[(hb * 16 + qbi) * 64 + t] = m;
            meanS[0][t] = m;
        }
    } else {
        if (t < 128) {
            const int d = t & 63, pair = t >> 6;      // pair 0: waves 0-1, 1: waves 2-3
            const int kbi = 2 * (by & 15) + pair;
            const float m =
                (sumbuf[2 * pair][d] + sumbuf[2 * pair + 1][d]) * (1.0f / 64.0f);
            km[(hb * 32 + kbi) * 64 + d] = m;
            meanS[pair][d] = m;
        }
    }
    __syncthreads();
    // fused min-cosine-to-mean: thread holds cols {lm, 32+lm} of 16 rows
    {
        const int mrow = (which == 0) ? 0 : (w >> 1);
        const float mv0 = meanS[mrow][lm], mv1 = meanS[mrow][32 + lm];
        float mn2 = mv0 * mv0 + mv1 * mv1;
        #pragma unroll
        for (int off = 1; off < 32; off <<= 1) mn2 += __shfl_xor(mn2, off);
        const float mnorm = sqrtf(mn2);
        float cmin = 1e30f;
        #pragma unroll
        for (int rg = 0; rg < 16; ++rg) {
            float dp = acc[0][rg] * mv0 + acc[1][rg] * mv1;
            float nn = acc[0][rg] * acc[0][rg] + acc[1][rg] * acc[1][rg];
            #pragma unroll
            for (int off = 1; off < 32; off <<= 1) {
                dp += __shfl_xor(dp, off);
                nn += __shfl_xor(nn, off);
            }
            const float cosv = dp / ((sqrtf(nn) + 1e-6f) * (mnorm + 1e-6f));
            cmin = fminf(cmin, cosv);
        }
        cmin = fminf(cmin, __shfl_xor(cmin, 32));
        if (l == 0) wminS[w] = cmin;
    }
    __syncthreads();
    if (t == 0) {
        if (which == 0) {
            qs[hb * 16 + (by & 15)] =
                fminf(fminf(wminS[0], wminS[1]), fminf(wminS[2], wminS[3]));
        } else {
            ks[hb * 32 + 2 * (by & 15)]     = fminf(wminS[0], wminS[1]);
            ks[hb * 32 + 2 * (by & 15) + 1] = fminf(wminS[2], wminS[3]);
        }
    }
}

// ---------------------------------------------------------------------------
// Flash attention, bf16 MFMA, S^T form, exp2 softmax, inline mask (R14).
// ROUND-20: BARRIER-FREE main loop. R19 counters: attn 52us with MfmaUtil
// 12% / VALU 21% / HBM 2.5% / conflicts 0 -> latency+barrier bound (1 block
// per CU, all 8 waves in one barrier domain, 16 sync'd staging iterations).
// Fix: K/V in fragment-linear layout -> each A-frag is ONE coalesced 1KB
// wave load from L2 (K+V 1MB/bh, L2-resident). No LDS staging, no dbuf, no
// main-loop __syncthreads -- waves stream their klist stripe independently;
// compiler hoists the 16 independent frag loads per K-block.
// 512 threads = 8 waves = 2 q-col groups (qc) x 4 klist stripes (kq); wave
// processes whole 64-key blocks j = kq, kq+4, ... (no tail mf needed).
// Epilogue: 4-way partial reduce in dedicated LDS (unchanged logic).
// ---------------------------------------------------------------------------
__global__ __launch_bounds__(512, 2) void attn_kernel(
    const ushortT* __restrict__ qb, const ushortT* __restrict__ kfrag,
    const ushortT* __restrict__ vfrag,
    const float* __restrict__ qm, const float* __restrict__ km,
    const float* __restrict__ qs, const float* __restrict__ ks,
    ushortT* __restrict__ ob) {
    __shared__ __align__(16) uint4 ox[6 * 8 * 64];   // 48 KB bf16-packed partials
    __shared__ float lx[6 * 2 * 32];                 // 1.5 KB partial l
    __shared__ int klist[33];
    __shared__ float qmS[64];
    __shared__ float pnS[32];

    const int t = threadIdx.x;
    const int l = t & 63, w = t >> 6;
    const int lm = l & 31, lh = l >> 5;
    const int qc = w >> 2, kq = w & 3;        // q 64-group, klist stripe
    const int bh = blockIdx.x, qt = blockIdx.y;

    if (t < 64) qmS[t] = qm[((size_t)bh * 16 + qt) * 64 + t];

    // Q B-frags straight from global: wave qc owns q rows [64qc, 64qc+64)
    const ushortT* qg = qb + ((size_t)bh * 2048 + qt * 128) * 64;
    short8 qf[4][2];
    #pragma unroll
    for (int qh = 0; qh < 2; ++qh)
        #pragma unroll
        for (int ksd = 0; ksd < 4; ++ksd)
            qf[ksd][qh] = *(const short8*)(qg + (64 * qc + 32 * qh + lm) * 64 + 16 * ksd + 8 * lh);
    __syncthreads();   // qmS visible

    // inline mask row (wave 0, lanes < 32): pooled softmax + CDF keep
    if (w == 0 && l < 32) {
        const float* kmr = km + ((size_t)bh * 32 + l) * 64;
        float dot = 0.f;
        #pragma unroll
        for (int d = 0; d < 64; ++d) dot += qmS[d] * kmr[d];
        float mx = dot;
        #pragma unroll
        for (int off = 1; off < 32; off <<= 1) mx = fmaxf(mx, __shfl_xor(mx, off));
        const float e = expf(dot - mx);
        float sum = e;
        #pragma unroll
        for (int off = 1; off < 32; off <<= 1) sum += __shfl_xor(sum, off);
        const float pn = e * (1.0f / sum);
        pnS[l] = pn;
        float before = 0.f;
        #pragma unroll
        for (int j = 0; j < 32; ++j) {
            const float pj = pnS[j];
            if (pj > pn || (pj == pn && j < l)) before += pj;
        }
        const bool qfb = !(qs[bh * 16 + qt] > 0.6f);
        const bool kfb = !(ks[bh * 32 + l] > 0.6f);
        const bool keep = (before < 0.98f) || qfb || kfb;
        unsigned long long bal = __ballot(keep);
        if (keep) {
            const int rank = __popcll(bal & ((1ULL << l) - 1ULL));
            klist[rank] = l;
        }
        if (l == 0) klist[32] = __popcll(bal);
    }
    __syncthreads();   // klist visible

    const int cnt = klist[32];
    const ushortT* kfb = kfrag + (size_t)bh * 131072;
    const ushortT* vfb = vfrag + (size_t)bh * 131072;

    f32x16 oacc[2][2];
    oacc[0][0] = zero16(); oacc[1][0] = zero16();
    oacc[0][1] = zero16(); oacc[1][1] = zero16();
    float l_i[2] = {0.f, 0.f};

    for (int j = kq; j < cnt; j += 4) {
        const int kb = klist[j];
        const ushortT* kbase = kfb + kb * 4096;
        const ushortT* vbase = vfb + kb * 4096;
        #pragma unroll
        for (int kh = 0; kh < 2; ++kh) {
            // S^T = K * Q^T  (S already in log2e units), 32 keys this half
            f32x16 sacc[2];
            sacc[0] = zero16(); sacc[1] = zero16();
            #pragma unroll
            for (int ksd = 0; ksd < 4; ++ksd) {
                short8 kf = *(const short8*)(kbase + ((kh * 4 + ksd) << 9) + l * 8);
                sacc[0] = MFMA32(kf, qf[ksd][0], sacc[0]);
                sacc[1] = MFMA32(kf, qf[ksd][1], sacc[1]);
            }
            // p = exp2(s)
            uintT uu[2][4][2];   // [qh][rb][pair]
            #pragma unroll
            for (int qh = 0; qh < 2; ++qh) {
                float psum0 = 0.f, psum1 = 0.f;
                #pragma unroll
                for (int rp = 0; rp < 8; ++rp) {
                    const float e0 = __builtin_amdgcn_exp2f(sacc[qh][2 * rp]);
                    const float e1 = __builtin_amdgcn_exp2f(sacc[qh][2 * rp + 1]);
                    psum0 += e0; psum1 += e1;
                    uu[qh][rp >> 1][rp & 1] = pack2t(e0, e1);
                }
                float psum = psum0 + psum1;
                psum += __shfl_xor(psum, 32);
                l_i[qh] += psum;
            }
            // O^T += V^T * P^T ; P^T B-frag via lane pair-exchange
            #pragma unroll
            for (int ksk = 0; ksk < 2; ++ksk) {
                const int ksl = 2 * kh + ksk;
                short8 vf0 = *(const short8*)(vbase + (ksl << 9) + l * 8);
                short8 vf1 = *(const short8*)(vbase + ((4 + ksl) << 9) + l * 8);
                #pragma unroll
                for (int qh = 0; qh < 2; ++qh) {
                    const uintT kA = lh ? uu[qh][2 * ksk + 1][0] : uu[qh][2 * ksk][0];
                    const uintT kB = lh ? uu[qh][2 * ksk + 1][1] : uu[qh][2 * ksk][1];
                    const uintT sA = lh ? uu[qh][2 * ksk][0] : uu[qh][2 * ksk + 1][0];
                    const uintT sB = lh ? uu[qh][2 * ksk][1] : uu[qh][2 * ksk + 1][1];
                    const uintT rA = (uintT)__shfl_xor((int)sA, 32);
                    const uintT rB = (uintT)__shfl_xor((int)sB, 32);
                    union { uintT u[4]; short8 v; } cv;
                    if (lh == 0) { cv.u[0] = kA; cv.u[1] = kB; cv.u[2] = rA; cv.u[3] = rB; }
                    else         { cv.u[0] = rA; cv.u[1] = rB; cv.u[2] = kA; cv.u[3] = kB; }
                    oacc[0][qh] = MFMA32(vf0, cv.v, oacc[0][qh]);
                    oacc[1][qh] = MFMA32(vf1, cv.v, oacc[1][qh]);
                }
            }
        }
    }

    // ---- cross-kq reduction in LDS ----
    if (kq != 0) {
        const int wslot = qc * 3 + (kq - 1);
        #pragma unroll
        for (int dt = 0; dt < 2; ++dt)
            #pragma unroll
            for (int qh = 0; qh < 2; ++qh)
                #pragma unroll
                for (int g2 = 0; g2 < 2; ++g2) {
                    uint4 u;
                    u.x = pack2(oacc[dt][qh][8 * g2 + 0], oacc[dt][qh][8 * g2 + 1]);
                    u.y = pack2(oacc[dt][qh][8 * g2 + 2], oacc[dt][qh][8 * g2 + 3]);
                    u.z = pack2(oacc[dt][qh][8 * g2 + 4], oacc[dt][qh][8 * g2 + 5]);
                    u.w = pack2(oacc[dt][qh][8 * g2 + 6], oacc[dt][qh][8 * g2 + 7]);
                    ox[(wslot * 8 + (dt * 4 + qh * 2 + g2)) * 64 + l] = u;
                }
        if (lh == 0) {
            lx[(wslot * 2 + 0) * 32 + lm] = l_i[0];
            lx[(wslot * 2 + 1) * 32 + lm] = l_i[1];
        }
    }
    __syncthreads();
    if (kq == 0) {
        float lt[2] = {l_i[0], l_i[1]};
        #pragma unroll
        for (int p = 0; p < 3; ++p) {
            const int ws2 = qc * 3 + p;
            lt[0] += lx[(ws2 * 2 + 0) * 32 + lm];
            lt[1] += lx[(ws2 * 2 + 1) * 32 + lm];
            #pragma unroll
            for (int dt = 0; dt < 2; ++dt)
                #pragma unroll
                for (int qh = 0; qh < 2; ++qh)
                    #pragma unroll
                    for (int g2 = 0; g2 < 2; ++g2) {
                        uint4 u = ox[(ws2 * 8 + (dt * 4 + qh * 2 + g2)) * 64 + l];
                        oacc[dt][qh][8 * g2 + 0] += blo(u.x);
                        oacc[dt][qh][8 * g2 + 1] += bhi(u.x);
                        oacc[dt][qh][8 * g2 + 2] += blo(u.y);
                        oacc[dt][qh][8 * g2 + 3] += bhi(u.y);
                        oacc[dt][qh][8 * g2 + 4] += blo(u.z);
                        oacc[dt][qh][8 * g2 + 5] += bhi(u.z);
                        oacc[dt][qh][8 * g2 + 6] += blo(u.w);
                        oacc[dt][qh][8 * g2 + 7] += bhi(u.w);
                    }
        }
        #pragma unroll
        for (int qh = 0; qh < 2; ++qh) {
            const float inv = 1.0f / lt[qh];
            const int token = qt * 128 + qc * 64 + 32 * qh + lm;
            ushortT* orow = ob + ((size_t)bh * 2048 + token) * 64;
            #pragma unroll
            for (int dt = 0; dt < 2; ++dt)
                #pragma unroll
                for (int rp = 0; rp < 8; ++rp) {
                    const int d0 = 32 * dt + 8 * (rp >> 1) + 4 * lh + 2 * (rp & 1);
                    *(uintT*)(orow + d0) =
                        pack2(oacc[dt][qh][2 * rp] * inv, oacc[dt][qh][2 * rp + 1] * inv);
                }
        }
    }
}

// ---------------------------------------------------------------------------
// Proj GEMM: 64x64 tiles, grid (8,64) = 512 blocks = 2 waves/SIMD.
// ob (gathered [4096,512] bf16) @ Wprojt^T + bias -> out fp32.
// ---------------------------------------------------------------------------
__global__ __launch_bounds__(256) void proj_gemm_kernel(
    const ushortT* __restrict__ ob, const ushortT* __restrict__ wpt,
    const float* __restrict__ bias, float* __restrict__ out) {
    __shared__ __align__(16) ushortT As[2][64 * 40];
    __shared__ __align__(16) ushortT Bs[2][64 * 40];
    const int t = threadIdx.x;
    const int l = t & 63, w = t >> 6;
    const int lm = l & 31, lh = l >> 5;
    const int rh = w & 1, ch = w >> 1;            // wave -> 32-row half, 32-col half
    const int rowbase = blockIdx.y * 64;
    const int colbase = blockIdx.x * 64;

    f32x16 acc = zero16();

    const int r = t >> 2, q4 = t & 3;             // row 0..63, k-quarter (8 elems)
    const int token = rowbase + r;
    const int b2 = token >> 11, lt = token & 2047;
    const int so = r * 40 + q4 * 8;
    const ushortT* obbase = ob + ((size_t)(b2 * 8) * 2048 + lt) * 64 + q4 * 8;
    const ushortT* Bg = wpt + (size_t)(colbase + r) * 512 + q4 * 8;

    uint4 a0, b0;
    a0 = *(const uint4*)(obbase);
    b0 = *(const uint4*)(Bg);
    *(uint4*)(&As[0][so]) = a0;
    *(uint4*)(&Bs[0][so]) = b0;

    for (int k0 = 0; k0 < 512; k0 += 32) {
        const int cur = (k0 >> 5) & 1;
        __syncthreads();
        if (k0 < 480) {
            const int kn = k0 + 32;
            const ushortT* Ag = obbase + (size_t)(kn >> 6) * 131072 + (kn & 63);
            a0 = *(const uint4*)(Ag);
            b0 = *(const uint4*)(Bg + kn);
        }
        #pragma unroll
        for (int ks2 = 0; ks2 < 2; ++ks2) {
            const int ko = 16 * ks2 + 8 * lh;
            short8 af = *(const short8*)(&As[cur][(32 * rh + lm) * 40 + ko]);
            short8 bf = *(const short8*)(&Bs[cur][(32 * ch + lm) * 40 + ko]);
            acc = MFMA32(af, bf, acc);
        }
        if (k0 < 480) {
            const int nxt = cur ^ 1;
            *(uint4*)(&As[nxt][so]) = a0;
            *(uint4*)(&Bs[nxt][so]) = b0;
        }
    }
    const int c = colbase + 32 * ch + lm;
    const float bb = bias[c];
    #pragma unroll
    for (int rg = 0; rg < 16; ++rg) {
        const int row_local = 32 * rh + (rg & 3) + 8 * (rg >> 2) + 4 * lh;
        out[(size_t)(rowbase + row_local) * 512 + c] = acc[rg] + bb;
    }
}

// ---------------------------------------------------------------------------
extern "C" void kernel_launch(void* const* d_in, const int* in_sizes, int n_in,
                              void* d_out, int out_size, void* d_ws, size_t ws_size,
                              hipStream_t stream) {
    const float* x     = (const float*)d_in[0];
    const float* Wqkv  = (const float*)d_in[1];
    const float* bqkv  = (const float*)d_in[2];
    const float* Wproj = (const float*)d_in[3];
    const float* bproj = (const float*)d_in[4];
    float* out = (float*)d_out;

    char* w = (char*)d_ws;
    ushortT* xb     = (ushortT*)(w);                    // 4 MB
    ushortT* wqkvt  = (ushortT*)(w + 4194304);          // 1.5 MB
    ushortT* wprojt = (ushortT*)(w + 5767168);          // 0.5 MB
    ushortT* qb     = (ushortT*)(w + 6291456);          // 4 MB (scaled 0.125*log2e)
    ushortT* kfrag  = (ushortT*)(w + 10485760);         // 4 MB (fragment-linear K)
    ushortT* vfrag  = (ushortT*)(w + 14680064);         // 4 MB (fragment-linear V)
    ushortT* ob     = (ushortT*)(w + 18874368);         // 4 MB (final attention output)
    float*   qm     = (float*)(w + 23068672);           // 64 KB
    float*   km     = (float*)(w + 23134208);           // 128 KB
    float*   qs     = (float*)(w + 36406272);           // 1 KB
    float*   ks     = (float*)(w + 36407296);           // 2 KB

    prep_kernel<<<3072, 256, 0, stream>>>(x, xb, Wqkv, wqkvt, Wproj, wprojt);
    qkv_gemm_kernel<<<dim3(24, 32), 256, 0, stream>>>(xb, wqkvt, bqkv, qb, kfrag, vfrag,
                                                      qm, km, qs, ks);
    attn_kernel<<<dim3(16, 16), 512, 0, stream>>>(qb, kfrag, vfrag, qm, km, qs, ks, ob);
    proj_gemm_kernel<<<dim3(8, 64), 256, 0, stream>>>(ob, wprojt, bproj, out);
}